// Round 1
// baseline (38277.719 us; speedup 1.0000x reference)
//
#include <hip/hip_runtime.h>

#define B_ 64
#define T_ 1024
#define I_ 512
#define H_ 1024
#define O_ 512
#define BH (B_*H_)   // 65536

using short8 = __attribute__((ext_vector_type(8))) short;
using f32x4  = __attribute__((ext_vector_type(4))) float;

__device__ __forceinline__ unsigned short f2b(float f) {
  unsigned int u = __float_as_uint(f);
  u = (u + 0x7fffu + ((u >> 16) & 1u)) >> 16;
  return (unsigned short)u;
}
__device__ __forceinline__ float b2f(unsigned short h) {
  return __uint_as_float(((unsigned int)h) << 16);
}

// ---------- cast kernels ----------
__global__ void cast4_kernel(const float* __restrict__ src, ushort* __restrict__ dst, int n4) {
  int i = blockIdx.x * 256 + threadIdx.x;
  if (i >= n4) return;
  float4 v = ((const float4*)src)[i];
  ushort4 o; o.x = f2b(v.x); o.y = f2b(v.y); o.z = f2b(v.z); o.w = f2b(v.w);
  ((ushort4*)dst)[i] = o;
}

// extract W_gate[:, H:2H] -> bf16 [H][H] row-major
__global__ void cast_gate_kernel(const float* __restrict__ src, ushort* __restrict__ dst) {
  int i = blockIdx.x * 256 + threadIdx.x;   // over H*H/4 = 262144
  int row = i >> 8, k4 = (i & 255) << 2;
  float4 v = *(const float4*)(src + (size_t)row * 2048 + 1024 + k4);
  ushort4 o; o.x = f2b(v.x); o.y = f2b(v.y); o.z = f2b(v.z); o.w = f2b(v.w);
  ((ushort4*)dst)[((size_t)row << 8) + (k4 >> 2)] = o;
}

// ---------- generic bf16 MFMA GEMM: C[M,N] = A[M,K] @ W[N,K]^T + bias ----------
// grid: (N/64, M/64), block 256 (4 waves). wave w owns m-subtile rows r0+16w..+15, all 64 cols.
// modeA: 0 = A bf16 row-major pitch K; 2 = A fp32, row r -> inputs row (b=r&63, t=r>>6), pitch K
// modeC: 0 = bf16 store pitch N; 1 = fp32 store at [b*T*O + t*O + n] (b=r&63, t=r>>6)
__global__ __launch_bounds__(256)
void gemm_bt(const void* __restrict__ A, const ushort* __restrict__ W,
             const float* __restrict__ bias, void* __restrict__ Cout,
             int M, int N, int K, int modeA, int modeC)
{
  int wave = threadIdx.x >> 6, lane = threadIdx.x & 63;
  int q = lane >> 4, col = lane & 15;
  int r0 = blockIdx.y * 64 + wave * 16;
  int n0 = blockIdx.x * 64;
  int arow = r0 + col;

  const ushort* Ab = nullptr;
  const float*  Af = nullptr;
  if (modeA == 0) {
    Ab = (const ushort*)A + (size_t)arow * K + q * 8;
  } else {
    int b = arow & 63, t = arow >> 6;
    Af = (const float*)A + ((size_t)b * T_ + t) * (size_t)K + q * 8;
  }
  const ushort* Wp = W + (size_t)(n0 + col) * K + q * 8;

  f32x4 acc[4];
  #pragma unroll
  for (int nt = 0; nt < 4; ++nt) acc[nt] = (f32x4){0.f, 0.f, 0.f, 0.f};

  if (modeA == 0) {
    for (int k0 = 0; k0 < K; k0 += 32) {
      short8 af = *(const short8*)(Ab + k0);
      #pragma unroll
      for (int nt = 0; nt < 4; ++nt) {
        short8 bf_ = *(const short8*)(Wp + (size_t)nt * 16 * K + k0);
        acc[nt] = __builtin_amdgcn_mfma_f32_16x16x32_bf16(af, bf_, acc[nt], 0, 0, 0);
      }
    }
  } else {
    for (int k0 = 0; k0 < K; k0 += 32) {
      float4 f0 = *(const float4*)(Af + k0);
      float4 f1 = *(const float4*)(Af + k0 + 4);
      short8 af;
      af[0] = (short)f2b(f0.x); af[1] = (short)f2b(f0.y);
      af[2] = (short)f2b(f0.z); af[3] = (short)f2b(f0.w);
      af[4] = (short)f2b(f1.x); af[5] = (short)f2b(f1.y);
      af[6] = (short)f2b(f1.z); af[7] = (short)f2b(f1.w);
      #pragma unroll
      for (int nt = 0; nt < 4; ++nt) {
        short8 bf_ = *(const short8*)(Wp + (size_t)nt * 16 * K + k0);
        acc[nt] = __builtin_amdgcn_mfma_f32_16x16x32_bf16(af, bf_, acc[nt], 0, 0, 0);
      }
    }
  }

  #pragma unroll
  for (int nt = 0; nt < 4; ++nt) {
    int n = n0 + nt * 16 + col;
    float bv = bias[n];
    #pragma unroll
    for (int r = 0; r < 4; ++r) {
      int row = r0 + q * 4 + r;
      float v = acc[nt][r] + bv;
      if (modeC == 0) {
        ((ushort*)Cout)[(size_t)row * N + n] = f2b(v);
      } else {
        int b = row & 63, t = row >> 6;
        ((float*)Cout)[(size_t)b * (T_ * O_) + (size_t)t * O_ + n] = v;
      }
    }
  }
}

// ---------- persistent scan kernel ----------
// 512 WGs x 64 threads (1 wave). group g = blockIdx&7 (XCD via %8 heuristic),
// member m = blockIdx>>3. Group owns batches [8g,8g+8); member owns cols [16m,16m+16).
// Wg_h cols resident in LDS in B-frag order; h staged per step in A-frag order.
// Sync: per-member monotonic flag = #published h states (device-scope acq/rel).
__global__ __launch_bounds__(64)
void scan_kernel(const ushort* __restrict__ z, const ushort* __restrict__ a,
                 ushort* __restrict__ hbuf, const float* __restrict__ Wgate,
                 const float* __restrict__ h0, float* __restrict__ hfinal,
                 int* __restrict__ flags)
{
  __shared__ __align__(16) short Wf[32 * 64 * 8];  // 32KB: [ks][lane][8]
  __shared__ __align__(16) short hf[32 * 64 * 8];  // 32KB: [ks][lane][8], rows>=8 stay 0

  const int tid = threadIdx.x;
  const int g = blockIdx.x & 7;
  const int member = blockIdx.x >> 3;
  const int b0 = g << 3;
  const int n0 = member << 4;
  const int lane = tid;          // 64-thread block = 1 wave
  const int q = lane >> 4, col = lane & 15;

  short8* hfv = (short8*)hf;
  short8* wfv = (short8*)Wf;

  // zero hf (invalid rows must be 0 for the MFMA)
  {
    short8 zz = {0,0,0,0,0,0,0,0};
    #pragma unroll
    for (int i = 0; i < 32; ++i) hfv[tid + 64 * i] = zz;
  }

  // load Wg_h[n0+col][*] into B-frag layout (once)
  {
    const float* wsrc = Wgate + (size_t)(n0 + col) * 2048 + (q * 8);
    for (int ks = 0; ks < 32; ++ks) {
      float4 w0 = *(const float4*)(wsrc + ks * 32);
      float4 w1 = *(const float4*)(wsrc + ks * 32 + 4);
      short8 v;
      v[0] = (short)f2b(w0.x); v[1] = (short)f2b(w0.y);
      v[2] = (short)f2b(w0.z); v[3] = (short)f2b(w0.w);
      v[4] = (short)f2b(w1.x); v[5] = (short)f2b(w1.y);
      v[6] = (short)f2b(w1.z); v[7] = (short)f2b(w1.w);
      wfv[ks * 64 + lane] = v;
    }
  }

  // publish h_0 slice (b0..b0+7) x (n0..n0+15) as bf16
  for (int i = tid; i < 128; i += 64) {
    int b = b0 + (i >> 4);
    int n = n0 + (i & 15);
    hbuf[(size_t)b * H_ + n] = f2b(h0[(size_t)b * H_ + n]);
  }
  __threadfence();
  if (tid == 0)
    __hip_atomic_store(&flags[(g << 6) + member], 1, __ATOMIC_RELEASE, __HIP_MEMORY_SCOPE_AGENT);

  const int fidx = (g << 6) + lane;   // lane <-> peer member

  for (int t = 1; t <= T_; ++t) {
    // wait until all 64 members published h_{t-1}
    for (;;) {
      int v = __hip_atomic_load(&flags[fidx], __ATOMIC_ACQUIRE, __HIP_MEMORY_SCOPE_AGENT);
      if (__ballot(v < t) == 0ull) break;
      __builtin_amdgcn_s_sleep(1);
    }

    // stage h_{t-1}[b0..b0+7][0..1023] into A-frag layout
    {
      const ushort* hsrc = hbuf + (size_t)(t - 1) * BH + (size_t)b0 * H_;
      #pragma unroll
      for (int i = 0; i < 16; ++i) {
        int c = tid + 64 * i;          // 0..1023 chunks of 8 elems
        int b = c >> 7;
        int k8 = (c & 127) << 3;
        short8 v = *(const short8*)(hsrc + (size_t)b * H_ + k8);
        int ks = k8 >> 5, qq = (k8 >> 3) & 3;
        hfv[ks * 64 + qq * 16 + b] = v;
      }
    }

    // S[b][n] = sum_k h_prev[b][k] * Wg_h[n][k]
    f32x4 acc0 = {0.f,0.f,0.f,0.f}, acc1 = {0.f,0.f,0.f,0.f};
    #pragma unroll 4
    for (int ks = 0; ks < 32; ks += 2) {
      acc0 = __builtin_amdgcn_mfma_f32_16x16x32_bf16(hfv[ks * 64 + lane],
                                                     wfv[ks * 64 + lane], acc0, 0, 0, 0);
      acc1 = __builtin_amdgcn_mfma_f32_16x16x32_bf16(hfv[(ks + 1) * 64 + lane],
                                                     wfv[(ks + 1) * 64 + lane], acc1, 0, 0, 0);
    }
    f32x4 S = acc0 + acc1;

    // epilogue: rows 0..7 live in quads 0,1 (row = q*4+reg), col = lane&15
    if (q < 2) {
      int n = n0 + col;
      #pragma unroll
      for (int r = 0; r < 4; ++r) {
        int b = b0 + q * 4 + r;
        size_t idx = (size_t)(t - 1) * BH + (size_t)b * H_ + n;
        float zv = b2f(z[idx]);
        float av = b2f(a[idx]);
        float hp = b2f(hbuf[idx]);
        float x  = S[r] + av;
        float u  = 1.0f / (1.0f + __expf(-x));
        float hn = u * hp + (1.0f - u) * zv;
        hbuf[(size_t)t * BH + (size_t)b * H_ + n] = f2b(hn);
        if (t == T_) hfinal[(size_t)b * H_ + n] = hn;
      }
    }
    __threadfence();
    if (tid == 0)
      __hip_atomic_store(&flags[(g << 6) + member], t + 1, __ATOMIC_RELEASE, __HIP_MEMORY_SCOPE_AGENT);
  }
}

// ---------- launcher ----------
extern "C" void kernel_launch(void* const* d_in, const int* in_sizes, int n_in,
                              void* d_out, int out_size, void* d_ws, size_t ws_size,
                              hipStream_t stream) {
  const float* inputs = (const float*)d_in[0];
  const float* h0     = (const float*)d_in[1];
  const float* W_in   = (const float*)d_in[2];
  const float* b_in   = (const float*)d_in[3];
  const float* W_gate = (const float*)d_in[4];
  const float* b_gate = (const float*)d_in[5];
  const float* W_out  = (const float*)d_in[6];
  const float* b_out  = (const float*)d_in[7];

  char* ws = (char*)d_ws;
  ushort* Winbf  = (ushort*)(ws + 0);                        // 1 MB
  ushort* Wgzbf  = (ushort*)(ws + (1u << 20));               // 2 MB
  ushort* Woutbf = (ushort*)(ws + 3 * (1u << 20));           // 1 MB
  ushort* z_bf   = (ushort*)(ws + 4 * (1u << 20));           // 128 MB
  ushort* a_bf   = (ushort*)(ws + (size_t)4 * (1u << 20) + (size_t)134217728);
  ushort* hbuf   = (ushort*)(ws + (size_t)4 * (1u << 20) + (size_t)2 * 134217728);
  int*    flags  = (int*)   (ws + (size_t)4 * (1u << 20) + (size_t)2 * 134217728 + (size_t)134348800);

  hipMemsetAsync(flags, 0, 8 * 64 * sizeof(int), stream);

  // weight casts
  cast4_kernel<<<dim3((H_ * I_ / 4 + 255) / 256), dim3(256), 0, stream>>>(W_in, Winbf, H_ * I_ / 4);
  cast4_kernel<<<dim3((O_ * H_ / 4 + 255) / 256), dim3(256), 0, stream>>>(W_out, Woutbf, O_ * H_ / 4);
  cast_gate_kernel<<<dim3(H_ * H_ / 4 / 256), dim3(256), 0, stream>>>(W_gate, Wgzbf);

  // G1: z[(t,b),h] = inputs[b,t,:] @ W_in^T + b_in   (A fp32 remapped)
  gemm_bt<<<dim3(H_ / 64, (B_ * T_) / 64), dim3(256), 0, stream>>>(
      (const void*)inputs, Winbf, b_in, (void*)z_bf, B_ * T_, H_, I_, 2, 0);

  // G2: a = z @ Wg_z^T + b_gate
  gemm_bt<<<dim3(H_ / 64, (B_ * T_) / 64), dim3(256), 0, stream>>>(
      (const void*)z_bf, Wgzbf, b_gate, (void*)a_bf, B_ * T_, H_, H_, 0, 0);

  // scan (cooperative: 512 co-resident WGs required)
  {
    float* hfinal = (float*)d_out + (size_t)B_ * T_ * O_;
    const ushort* zc = z_bf; const ushort* ac = a_bf;
    ushort* hb = hbuf; const float* wg = W_gate; const float* h0c = h0;
    int* flg = flags;
    void* sargs[7] = { (void*)&zc, (void*)&ac, (void*)&hb, (void*)&wg,
                       (void*)&h0c, (void*)&hfinal, (void*)&flg };
    hipLaunchCooperativeKernel((const void*)scan_kernel, dim3(512), dim3(64), sargs, 0, stream);
  }

  // G3: outs[b,t,o] = hs[(t,b),:] @ W_out^T + b_out  (A = hbuf[1..T])
  gemm_bt<<<dim3(O_ / 64, (B_ * T_) / 64), dim3(256), 0, stream>>>(
      (const void*)(hbuf + BH), Woutbf, b_out, d_out, B_ * T_, O_, H_, 0, 1);
}

// Round 2
// 18409.637 us; speedup vs baseline: 2.0792x; 2.0792x over previous
//
#include <hip/hip_runtime.h>

#define B_ 64
#define T_ 1024
#define I_ 512
#define H_ 1024
#define O_ 512
#define BH (B_*H_)   // 65536

using short8 = __attribute__((ext_vector_type(8))) short;
using f32x4  = __attribute__((ext_vector_type(4))) float;

__device__ __forceinline__ unsigned short f2b(float f) {
  unsigned int u = __float_as_uint(f);
  u = (u + 0x7fffu + ((u >> 16) & 1u)) >> 16;
  return (unsigned short)u;
}
__device__ __forceinline__ float b2f(unsigned short h) {
  return __uint_as_float(((unsigned int)h) << 16);
}

// ---------- cast kernels ----------
__global__ void cast4_kernel(const float* __restrict__ src, ushort* __restrict__ dst, int n4) {
  int i = blockIdx.x * 256 + threadIdx.x;
  if (i >= n4) return;
  float4 v = ((const float4*)src)[i];
  ushort4 o; o.x = f2b(v.x); o.y = f2b(v.y); o.z = f2b(v.z); o.w = f2b(v.w);
  ((ushort4*)dst)[i] = o;
}

// extract W_gate[:, H:2H] -> bf16 [H][H] row-major
__global__ void cast_gate_kernel(const float* __restrict__ src, ushort* __restrict__ dst) {
  int i = blockIdx.x * 256 + threadIdx.x;   // over H*H/4 = 262144
  int row = i >> 8, k4 = (i & 255) << 2;
  float4 v = *(const float4*)(src + (size_t)row * 2048 + 1024 + k4);
  ushort4 o; o.x = f2b(v.x); o.y = f2b(v.y); o.z = f2b(v.z); o.w = f2b(v.w);
  ((ushort4*)dst)[((size_t)row << 8) + (k4 >> 2)] = o;
}

// ---------- generic bf16 MFMA GEMM: C[M,N] = A[M,K] @ W[N,K]^T + bias ----------
__global__ __launch_bounds__(256)
void gemm_bt(const void* __restrict__ A, const ushort* __restrict__ W,
             const float* __restrict__ bias, void* __restrict__ Cout,
             int M, int N, int K, int modeA, int modeC)
{
  int wave = threadIdx.x >> 6, lane = threadIdx.x & 63;
  int q = lane >> 4, col = lane & 15;
  int r0 = blockIdx.y * 64 + wave * 16;
  int n0 = blockIdx.x * 64;
  int arow = r0 + col;

  const ushort* Ab = nullptr;
  const float*  Af = nullptr;
  if (modeA == 0) {
    Ab = (const ushort*)A + (size_t)arow * K + q * 8;
  } else {
    int b = arow & 63, t = arow >> 6;
    Af = (const float*)A + ((size_t)b * T_ + t) * (size_t)K + q * 8;
  }
  const ushort* Wp = W + (size_t)(n0 + col) * K + q * 8;

  f32x4 acc[4];
  #pragma unroll
  for (int nt = 0; nt < 4; ++nt) acc[nt] = (f32x4){0.f, 0.f, 0.f, 0.f};

  if (modeA == 0) {
    for (int k0 = 0; k0 < K; k0 += 32) {
      short8 af = *(const short8*)(Ab + k0);
      #pragma unroll
      for (int nt = 0; nt < 4; ++nt) {
        short8 bf_ = *(const short8*)(Wp + (size_t)nt * 16 * K + k0);
        acc[nt] = __builtin_amdgcn_mfma_f32_16x16x32_bf16(af, bf_, acc[nt], 0, 0, 0);
      }
    }
  } else {
    for (int k0 = 0; k0 < K; k0 += 32) {
      float4 f0 = *(const float4*)(Af + k0);
      float4 f1 = *(const float4*)(Af + k0 + 4);
      short8 af;
      af[0] = (short)f2b(f0.x); af[1] = (short)f2b(f0.y);
      af[2] = (short)f2b(f0.z); af[3] = (short)f2b(f0.w);
      af[4] = (short)f2b(f1.x); af[5] = (short)f2b(f1.y);
      af[6] = (short)f2b(f1.z); af[7] = (short)f2b(f1.w);
      #pragma unroll
      for (int nt = 0; nt < 4; ++nt) {
        short8 bf_ = *(const short8*)(Wp + (size_t)nt * 16 * K + k0);
        acc[nt] = __builtin_amdgcn_mfma_f32_16x16x32_bf16(af, bf_, acc[nt], 0, 0, 0);
      }
    }
  }

  #pragma unroll
  for (int nt = 0; nt < 4; ++nt) {
    int n = n0 + nt * 16 + col;
    float bv = bias[n];
    #pragma unroll
    for (int r = 0; r < 4; ++r) {
      int row = r0 + q * 4 + r;
      float v = acc[nt][r] + bv;
      if (modeC == 0) {
        ((ushort*)Cout)[(size_t)row * N + n] = f2b(v);
      } else {
        int b = row & 63, t = row >> 6;
        ((float*)Cout)[(size_t)b * (T_ * O_) + (size_t)t * O_ + n] = v;
      }
    }
  }
}

// ---------- persistent scan kernel (round 2: relaxed-atomic IF mailbox) ----------
// 512 WGs x 64 threads. group g = blockIdx&7, member m = blockIdx>>3.
// Group owns batches [8g,8g+8); member owns cols [16m,16m+16).
// h published as relaxed agent atomics (sc0 sc1 -> coherent at IF, NO cache
// maintenance). Consumers plain-load write-once addresses (no stale-line risk).
// h MFMA A-frags loaded DIRECTLY from global (no LDS staging -> no conflicts).
__global__ __launch_bounds__(64)
void scan_kernel(const ushort* __restrict__ z, const ushort* __restrict__ a,
                 ushort* __restrict__ hbuf, const float* __restrict__ Wgate,
                 const float* __restrict__ h0, float* __restrict__ hfinal,
                 int* __restrict__ flags)
{
  __shared__ __align__(16) short Wf[32 * 64 * 8];  // 32KB: [ks][lane][8]

  const int tid = threadIdx.x;
  const int g = blockIdx.x & 7;
  const int member = blockIdx.x >> 3;
  const int b0 = g << 3;
  const int n0 = member << 4;
  const int lane = tid;          // 64-thread block = 1 wave
  const int q = lane >> 4, col = lane & 15;

  short8* wfv = (short8*)Wf;

  // load Wg_h[n0+col][*] into B-frag layout (once); write slot=lane: conflict-free
  {
    const float* wsrc = Wgate + (size_t)(n0 + col) * 2048 + (q * 8);
    for (int ks = 0; ks < 32; ++ks) {
      float4 w0 = *(const float4*)(wsrc + ks * 32);
      float4 w1 = *(const float4*)(wsrc + ks * 32 + 4);
      short8 v;
      v[0] = (short)f2b(w0.x); v[1] = (short)f2b(w0.y);
      v[2] = (short)f2b(w0.z); v[3] = (short)f2b(w0.w);
      v[4] = (short)f2b(w1.x); v[5] = (short)f2b(w1.y);
      v[6] = (short)f2b(w1.z); v[7] = (short)f2b(w1.w);
      wfv[ks * 64 + lane] = v;
    }
  }

  // publish h_0 slice (paired bf16 dwords, relaxed agent atomics -> IF)
  {
    int b = b0 + (tid >> 3);
    int n = n0 + (tid & 7) * 2;
    const float* hp0 = h0 + (size_t)b * H_ + n;
    unsigned int dw = (unsigned int)f2b(hp0[0]) | ((unsigned int)f2b(hp0[1]) << 16);
    __hip_atomic_store((unsigned int*)(hbuf + (size_t)b * H_ + n), dw,
                       __ATOMIC_RELAXED, __HIP_MEMORY_SCOPE_AGENT);
  }

  // own h_prev values carried in fp32 registers
  float hp[4] = {0.f, 0.f, 0.f, 0.f};
  if (q < 2) {
    #pragma unroll
    for (int r = 0; r < 4; ++r)
      hp[r] = h0[(size_t)(b0 + q * 4 + r) * H_ + n0 + col];
  }

  __builtin_amdgcn_s_waitcnt(0);  // drain data stores before flag
  if (tid == 0)
    __hip_atomic_store(&flags[(g << 6) + member], 1, __ATOMIC_RELEASE, __HIP_MEMORY_SCOPE_AGENT);

  const int fidx = (g << 6) + lane;   // lane <-> peer member
  const short8 zero8 = {0, 0, 0, 0, 0, 0, 0, 0};

  for (int t = 1; t <= T_; ++t) {
    // prefetch z/a (flag-independent; hides HBM latency behind the poll)
    float zv[4], av[4];
    if (q < 2) {
      const size_t base = (size_t)(t - 1) * BH + (size_t)(b0 + q * 4) * H_ + n0 + col;
      #pragma unroll
      for (int r = 0; r < 4; ++r) {
        zv[r] = b2f(z[base + (size_t)r * H_]);
        av[r] = b2f(a[base + (size_t)r * H_]);
      }
    }

    // wait until all 64 members published h_{t-1} (relaxed polls: no cache maintenance)
    for (;;) {
      int v = __hip_atomic_load(&flags[fidx], __ATOMIC_RELAXED, __HIP_MEMORY_SCOPE_AGENT);
      if (__ballot(v < t) == 0ull) break;
      __builtin_amdgcn_s_sleep(1);
    }
    __builtin_amdgcn_fence(__ATOMIC_ACQUIRE, "workgroup");  // compiler barrier; no L2 inval

    // direct global loads of MFMA A-frags: h[b=col][k=ks*32+q*8 ..+8)
    const ushort* hrow = hbuf + (size_t)(t - 1) * BH + (size_t)(b0 + col) * H_ + q * 8;
    f32x4 acc0 = {0.f, 0.f, 0.f, 0.f}, acc1 = {0.f, 0.f, 0.f, 0.f};
    #pragma unroll
    for (int ks = 0; ks < 32; ks += 2) {
      short8 h0f = (col < 8) ? *(const short8*)(hrow + ks * 32) : zero8;
      short8 h1f = (col < 8) ? *(const short8*)(hrow + (ks + 1) * 32) : zero8;
      acc0 = __builtin_amdgcn_mfma_f32_16x16x32_bf16(h0f, wfv[ks * 64 + lane], acc0, 0, 0, 0);
      acc1 = __builtin_amdgcn_mfma_f32_16x16x32_bf16(h1f, wfv[(ks + 1) * 64 + lane], acc1, 0, 0, 0);
    }
    f32x4 S = acc0 + acc1;

    // epilogue: rows 0..7 live in quads 0,1 (row = q*4+r), col = lane&15
    if (q < 2) {
      #pragma unroll
      for (int r = 0; r < 4; ++r) {
        int b = b0 + q * 4 + r;
        float x  = S[r] + av[r];
        float u  = 1.0f / (1.0f + __expf(-x));
        float hn = u * hp[r] + (1.0f - u) * zv[r];
        hp[r] = hn;                          // fp32 carry
        unsigned int own = f2b(hn);
        unsigned int other = ((unsigned int)__shfl_xor((int)own, 1, 64)) & 0xffffu;
        if ((col & 1) == 0) {
          unsigned int dw = own | (other << 16);
          __hip_atomic_store((unsigned int*)(hbuf + (size_t)t * BH + (size_t)b * H_ + n0 + col),
                             dw, __ATOMIC_RELAXED, __HIP_MEMORY_SCOPE_AGENT);
        }
        if (t == T_) hfinal[(size_t)b * H_ + n0 + col] = hn;
      }
    }
    __builtin_amdgcn_s_waitcnt(0);  // all lanes' data stores acked before flag
    if (tid == 0)
      __hip_atomic_store(&flags[(g << 6) + member], t + 1, __ATOMIC_RELEASE, __HIP_MEMORY_SCOPE_AGENT);
  }
}

// ---------- launcher ----------
extern "C" void kernel_launch(void* const* d_in, const int* in_sizes, int n_in,
                              void* d_out, int out_size, void* d_ws, size_t ws_size,
                              hipStream_t stream) {
  const float* inputs = (const float*)d_in[0];
  const float* h0     = (const float*)d_in[1];
  const float* W_in   = (const float*)d_in[2];
  const float* b_in   = (const float*)d_in[3];
  const float* W_gate = (const float*)d_in[4];
  const float* b_gate = (const float*)d_in[5];
  const float* W_out  = (const float*)d_in[6];
  const float* b_out  = (const float*)d_in[7];

  char* ws = (char*)d_ws;
  ushort* Winbf  = (ushort*)(ws + 0);                        // 1 MB
  ushort* Wgzbf  = (ushort*)(ws + (1u << 20));               // 2 MB
  ushort* Woutbf = (ushort*)(ws + 3 * (1u << 20));           // 1 MB
  ushort* z_bf   = (ushort*)(ws + 4 * (1u << 20));           // 128 MB
  ushort* a_bf   = (ushort*)(ws + (size_t)4 * (1u << 20) + (size_t)134217728);
  ushort* hbuf   = (ushort*)(ws + (size_t)4 * (1u << 20) + (size_t)2 * 134217728);
  int*    flags  = (int*)   (ws + (size_t)4 * (1u << 20) + (size_t)2 * 134217728 + (size_t)134348800);

  hipMemsetAsync(flags, 0, 8 * 64 * sizeof(int), stream);

  // weight casts
  cast4_kernel<<<dim3((H_ * I_ / 4 + 255) / 256), dim3(256), 0, stream>>>(W_in, Winbf, H_ * I_ / 4);
  cast4_kernel<<<dim3((O_ * H_ / 4 + 255) / 256), dim3(256), 0, stream>>>(W_out, Woutbf, O_ * H_ / 4);
  cast_gate_kernel<<<dim3(H_ * H_ / 4 / 256), dim3(256), 0, stream>>>(W_gate, Wgzbf);

  // G1: z[(t,b),h] = inputs[b,t,:] @ W_in^T + b_in   (A fp32 remapped)
  gemm_bt<<<dim3(H_ / 64, (B_ * T_) / 64), dim3(256), 0, stream>>>(
      (const void*)inputs, Winbf, b_in, (void*)z_bf, B_ * T_, H_, I_, 2, 0);

  // G2: a = z @ Wg_z^T + b_gate
  gemm_bt<<<dim3(H_ / 64, (B_ * T_) / 64), dim3(256), 0, stream>>>(
      (const void*)z_bf, Wgzbf, b_gate, (void*)a_bf, B_ * T_, H_, H_, 0, 0);

  // scan (cooperative: 512 co-resident WGs required)
  {
    float* hfinal = (float*)d_out + (size_t)B_ * T_ * O_;
    const ushort* zc = z_bf; const ushort* ac = a_bf;
    ushort* hb = hbuf; const float* wg = W_gate; const float* h0c = h0;
    int* flg = flags;
    void* sargs[7] = { (void*)&zc, (void*)&ac, (void*)&hb, (void*)&wg,
                       (void*)&h0c, (void*)&hfinal, (void*)&flg };
    hipLaunchCooperativeKernel((const void*)scan_kernel, dim3(512), dim3(64), sargs, 0, stream);
  }

  // G3: outs[b,t,o] = hs[(t,b),:] @ W_out^T + b_out  (A = hbuf[1..T])
  gemm_bt<<<dim3(O_ / 64, (B_ * T_) / 64), dim3(256), 0, stream>>>(
      (const void*)(hbuf + BH), Woutbf, b_out, d_out, B_ * T_, O_, H_, 0, 1);
}

// Round 3
// 10353.906 us; speedup vs baseline: 3.6969x; 1.7780x over previous
//
#include <hip/hip_runtime.h>

#define B_ 64
#define T_ 1024
#define I_ 512
#define H_ 1024
#define O_ 512
#define BH (B_*H_)   // 65536

using short8 = __attribute__((ext_vector_type(8))) short;
using f32x4  = __attribute__((ext_vector_type(4))) float;

__device__ __forceinline__ unsigned short f2b(float f) {
  unsigned int u = __float_as_uint(f);
  u = (u + 0x7fffu + ((u >> 16) & 1u)) >> 16;
  return (unsigned short)u;
}
__device__ __forceinline__ float b2f(unsigned short h) {
  return __uint_as_float(((unsigned int)h) << 16);
}

// wait only vmcnt==0 (gfx9 encoding: expcnt=7, lgkmcnt=0xF -> no wait on those)
#define WAIT_VM0() __builtin_amdgcn_s_waitcnt(0x0F70)

// ---------- cast kernels ----------
__global__ void cast4_kernel(const float* __restrict__ src, ushort* __restrict__ dst, int n4) {
  int i = blockIdx.x * 256 + threadIdx.x;
  if (i >= n4) return;
  float4 v = ((const float4*)src)[i];
  ushort4 o; o.x = f2b(v.x); o.y = f2b(v.y); o.z = f2b(v.z); o.w = f2b(v.w);
  ((ushort4*)dst)[i] = o;
}

// extract W_gate[:, H:2H] -> bf16 [H][H] row-major
__global__ void cast_gate_kernel(const float* __restrict__ src, ushort* __restrict__ dst) {
  int i = blockIdx.x * 256 + threadIdx.x;   // over H*H/4 = 262144
  int row = i >> 8, k4 = (i & 255) << 2;
  float4 v = *(const float4*)(src + (size_t)row * 2048 + 1024 + k4);
  ushort4 o; o.x = f2b(v.x); o.y = f2b(v.y); o.z = f2b(v.z); o.w = f2b(v.w);
  ((ushort4*)dst)[((size_t)row << 8) + (k4 >> 2)] = o;
}

// ---------- generic bf16 MFMA GEMM: C[M,N] = A[M,K] @ W[N,K]^T + bias ----------
__global__ __launch_bounds__(256)
void gemm_bt(const void* __restrict__ A, const ushort* __restrict__ W,
             const float* __restrict__ bias, void* __restrict__ Cout,
             int M, int N, int K, int modeA, int modeC)
{
  int wave = threadIdx.x >> 6, lane = threadIdx.x & 63;
  int q = lane >> 4, col = lane & 15;
  int r0 = blockIdx.y * 64 + wave * 16;
  int n0 = blockIdx.x * 64;
  int arow = r0 + col;

  const ushort* Ab = nullptr;
  const float*  Af = nullptr;
  if (modeA == 0) {
    Ab = (const ushort*)A + (size_t)arow * K + q * 8;
  } else {
    int b = arow & 63, t = arow >> 6;
    Af = (const float*)A + ((size_t)b * T_ + t) * (size_t)K + q * 8;
  }
  const ushort* Wp = W + (size_t)(n0 + col) * K + q * 8;

  f32x4 acc[4];
  #pragma unroll
  for (int nt = 0; nt < 4; ++nt) acc[nt] = (f32x4){0.f, 0.f, 0.f, 0.f};

  if (modeA == 0) {
    for (int k0 = 0; k0 < K; k0 += 32) {
      short8 af = *(const short8*)(Ab + k0);
      #pragma unroll
      for (int nt = 0; nt < 4; ++nt) {
        short8 bf_ = *(const short8*)(Wp + (size_t)nt * 16 * K + k0);
        acc[nt] = __builtin_amdgcn_mfma_f32_16x16x32_bf16(af, bf_, acc[nt], 0, 0, 0);
      }
    }
  } else {
    for (int k0 = 0; k0 < K; k0 += 32) {
      float4 f0 = *(const float4*)(Af + k0);
      float4 f1 = *(const float4*)(Af + k0 + 4);
      short8 af;
      af[0] = (short)f2b(f0.x); af[1] = (short)f2b(f0.y);
      af[2] = (short)f2b(f0.z); af[3] = (short)f2b(f0.w);
      af[4] = (short)f2b(f1.x); af[5] = (short)f2b(f1.y);
      af[6] = (short)f2b(f1.z); af[7] = (short)f2b(f1.w);
      #pragma unroll
      for (int nt = 0; nt < 4; ++nt) {
        short8 bf_ = *(const short8*)(Wp + (size_t)nt * 16 * K + k0);
        acc[nt] = __builtin_amdgcn_mfma_f32_16x16x32_bf16(af, bf_, acc[nt], 0, 0, 0);
      }
    }
  }

  #pragma unroll
  for (int nt = 0; nt < 4; ++nt) {
    int n = n0 + nt * 16 + col;
    float bv = bias[n];
    #pragma unroll
    for (int r = 0; r < 4; ++r) {
      int row = r0 + q * 4 + r;
      float v = acc[nt][r] + bv;
      if (modeC == 0) {
        ((ushort*)Cout)[(size_t)row * N + n] = f2b(v);
      } else {
        int b = row & 63, t = row >> 6;
        ((float*)Cout)[(size_t)b * (T_ * O_) + (size_t)t * O_ + n] = v;
      }
    }
  }
}

// ---------- scan round 3 ----------
// 4 groups x 16 batches. 128 WGs x 64 threads: member = blockIdx&63 owns cols
// [16m,16m+16); pair p = blockIdx>>6 owns groups {2p, 2p+1}, interleaved to
// hide publish/poll latency. Sync = relaxed agent atomics only:
// data publish (sc0 sc1, write-through) -> s_waitcnt vmcnt(0) -> relaxed flag.
// NO release/acquire agent fences in the loop (no buffer_wbl2 / buffer_inv).
__device__ __forceinline__ void scan_step(
    int t, int g, int b0, int n0, int lane, int q, int col,
    const short8* __restrict__ wfv, ushort* __restrict__ hbuf,
    float* __restrict__ hfinal, int* __restrict__ flags,
    const float zv[4], const float av[4], float hp[4])
{
  // wait until all 64 members published h_{t-1} for this group
  const int fidx = (g << 6) + lane;
  for (;;) {
    int v = __hip_atomic_load(&flags[fidx], __ATOMIC_RELAXED, __HIP_MEMORY_SCOPE_AGENT);
    if (__ballot(v < t) == 0ull) break;
    __builtin_amdgcn_s_sleep(1);
  }
  __builtin_amdgcn_fence(__ATOMIC_ACQUIRE, "workgroup");  // compiler barrier only

  // direct global loads of MFMA A-frags: h[b = b0+col][k = ks*32 + q*8 ..+8)
  const ushort* hrow = hbuf + (size_t)(t - 1) * BH + (size_t)(b0 + col) * H_ + q * 8;
  f32x4 acc0 = {0.f, 0.f, 0.f, 0.f}, acc1 = {0.f, 0.f, 0.f, 0.f};
  #pragma unroll
  for (int ks = 0; ks < 32; ks += 2) {
    short8 h0f = *(const short8*)(hrow + ks * 32);
    short8 h1f = *(const short8*)(hrow + (ks + 1) * 32);
    acc0 = __builtin_amdgcn_mfma_f32_16x16x32_bf16(h0f, wfv[ks * 64 + lane], acc0, 0, 0, 0);
    acc1 = __builtin_amdgcn_mfma_f32_16x16x32_bf16(h1f, wfv[(ks + 1) * 64 + lane], acc1, 0, 0, 0);
  }
  f32x4 S = acc0 + acc1;

  // epilogue: all 16 rows valid (row = q*4+r = batch), col = n
  #pragma unroll
  for (int r = 0; r < 4; ++r) {
    int b = b0 + q * 4 + r;
    float x  = S[r] + av[r];
    float u  = 1.0f / (1.0f + __expf(-x));
    float hn = u * hp[r] + (1.0f - u) * zv[r];
    hp[r] = hn;                          // fp32 carry
    unsigned int own = f2b(hn);
    unsigned int other = ((unsigned int)__shfl_xor((int)own, 1, 64)) & 0xffffu;
    if ((col & 1) == 0) {
      unsigned int dw = own | (other << 16);
      __hip_atomic_store((unsigned int*)(hbuf + (size_t)t * BH + (size_t)b * H_ + n0 + col),
                         dw, __ATOMIC_RELAXED, __HIP_MEMORY_SCOPE_AGENT);
    }
    if (t == T_) hfinal[(size_t)b * H_ + n0 + col] = hn;
  }
  WAIT_VM0();   // all lanes' publishes acked at coherence point; nothing dirty in L2
  if (lane == 0)
    __hip_atomic_store(&flags[(g << 6) + (n0 >> 4)], t + 1,
                       __ATOMIC_RELAXED, __HIP_MEMORY_SCOPE_AGENT);
}

__global__ __launch_bounds__(64)
void scan_kernel(const ushort* __restrict__ z, const ushort* __restrict__ a,
                 ushort* __restrict__ hbuf, const float* __restrict__ Wgate,
                 const float* __restrict__ h0, float* __restrict__ hfinal,
                 int* __restrict__ flags)
{
  __shared__ __align__(16) short Wf[32 * 64 * 8];  // 32KB: [ks][lane][8]

  const int tid = threadIdx.x;
  const int member = blockIdx.x & 63;
  const int pairid = blockIdx.x >> 6;          // 0 or 1
  const int gA = pairid * 2, gB = pairid * 2 + 1;
  const int b0A = gA << 4, b0B = gB << 4;
  const int n0 = member << 4;
  const int lane = tid;
  const int q = lane >> 4, col = lane & 15;

  short8* wfv = (short8*)Wf;

  // load Wg_h[n0+col][*] into B-frag layout (once); slot=lane: conflict-free
  {
    const float* wsrc = Wgate + (size_t)(n0 + col) * 2048 + (q * 8);
    for (int ks = 0; ks < 32; ++ks) {
      float4 w0 = *(const float4*)(wsrc + ks * 32);
      float4 w1 = *(const float4*)(wsrc + ks * 32 + 4);
      short8 v;
      v[0] = (short)f2b(w0.x); v[1] = (short)f2b(w0.y);
      v[2] = (short)f2b(w0.z); v[3] = (short)f2b(w0.w);
      v[4] = (short)f2b(w1.x); v[5] = (short)f2b(w1.y);
      v[6] = (short)f2b(w1.z); v[7] = (short)f2b(w1.w);
      wfv[ks * 64 + lane] = v;
    }
  }

  // publish h_0 (both groups), paired bf16 dwords, relaxed agent
  #pragma unroll
  for (int grp = 0; grp < 2; ++grp) {
    int b0 = grp ? b0B : b0A;
    #pragma unroll
    for (int i = 0; i < 2; ++i) {
      int idx = tid + 64 * i;                   // 0..127
      int b = b0 + (idx >> 3);
      int n = n0 + (idx & 7) * 2;
      const float* hp0 = h0 + (size_t)b * H_ + n;
      unsigned int dw = (unsigned int)f2b(hp0[0]) | ((unsigned int)f2b(hp0[1]) << 16);
      __hip_atomic_store((unsigned int*)(hbuf + (size_t)b * H_ + n), dw,
                         __ATOMIC_RELAXED, __HIP_MEMORY_SCOPE_AGENT);
    }
  }

  // own h_prev values in fp32 registers
  float hpA[4], hpB[4];
  #pragma unroll
  for (int r = 0; r < 4; ++r) {
    hpA[r] = h0[(size_t)(b0A + q * 4 + r) * H_ + n0 + col];
    hpB[r] = h0[(size_t)(b0B + q * 4 + r) * H_ + n0 + col];
  }

  WAIT_VM0();
  if (tid == 0) {
    __hip_atomic_store(&flags[(gA << 6) + member], 1, __ATOMIC_RELAXED, __HIP_MEMORY_SCOPE_AGENT);
    __hip_atomic_store(&flags[(gB << 6) + member], 1, __ATOMIC_RELAXED, __HIP_MEMORY_SCOPE_AGENT);
  }

  for (int t = 1; t <= T_; ++t) {
    // prefetch z/a for BOTH chains up front (flag-independent; hides HBM latency)
    float zvA[4], avA[4], zvB[4], avB[4];
    {
      const size_t baseA = (size_t)(t - 1) * BH + (size_t)(b0A + q * 4) * H_ + n0 + col;
      const size_t baseB = (size_t)(t - 1) * BH + (size_t)(b0B + q * 4) * H_ + n0 + col;
      #pragma unroll
      for (int r = 0; r < 4; ++r) {
        zvA[r] = b2f(z[baseA + (size_t)r * H_]);
        avA[r] = b2f(a[baseA + (size_t)r * H_]);
        zvB[r] = b2f(z[baseB + (size_t)r * H_]);
        avB[r] = b2f(a[baseB + (size_t)r * H_]);
      }
    }
    scan_step(t, gA, b0A, n0, lane, q, col, wfv, hbuf, hfinal, flags, zvA, avA, hpA);
    scan_step(t, gB, b0B, n0, lane, q, col, wfv, hbuf, hfinal, flags, zvB, avB, hpB);
  }
}

// ---------- launcher ----------
extern "C" void kernel_launch(void* const* d_in, const int* in_sizes, int n_in,
                              void* d_out, int out_size, void* d_ws, size_t ws_size,
                              hipStream_t stream) {
  const float* inputs = (const float*)d_in[0];
  const float* h0     = (const float*)d_in[1];
  const float* W_in   = (const float*)d_in[2];
  const float* b_in   = (const float*)d_in[3];
  const float* W_gate = (const float*)d_in[4];
  const float* b_gate = (const float*)d_in[5];
  const float* W_out  = (const float*)d_in[6];
  const float* b_out  = (const float*)d_in[7];

  char* ws = (char*)d_ws;
  ushort* Winbf  = (ushort*)(ws + 0);                        // 1 MB
  ushort* Wgzbf  = (ushort*)(ws + (1u << 20));               // 2 MB
  ushort* Woutbf = (ushort*)(ws + 3 * (1u << 20));           // 1 MB
  ushort* z_bf   = (ushort*)(ws + 4 * (1u << 20));           // 128 MB
  ushort* a_bf   = (ushort*)(ws + (size_t)4 * (1u << 20) + (size_t)134217728);
  ushort* hbuf   = (ushort*)(ws + (size_t)4 * (1u << 20) + (size_t)2 * 134217728);
  int*    flags  = (int*)   (ws + (size_t)4 * (1u << 20) + (size_t)2 * 134217728 + (size_t)134348800);

  hipMemsetAsync(flags, 0, 4 * 64 * sizeof(int), stream);

  // weight casts
  cast4_kernel<<<dim3((H_ * I_ / 4 + 255) / 256), dim3(256), 0, stream>>>(W_in, Winbf, H_ * I_ / 4);
  cast4_kernel<<<dim3((O_ * H_ / 4 + 255) / 256), dim3(256), 0, stream>>>(W_out, Woutbf, O_ * H_ / 4);
  cast_gate_kernel<<<dim3(H_ * H_ / 4 / 256), dim3(256), 0, stream>>>(W_gate, Wgzbf);

  // G1: z[(t,b),h] = inputs[b,t,:] @ W_in^T + b_in   (A fp32 remapped)
  gemm_bt<<<dim3(H_ / 64, (B_ * T_) / 64), dim3(256), 0, stream>>>(
      (const void*)inputs, Winbf, b_in, (void*)z_bf, B_ * T_, H_, I_, 2, 0);

  // G2: a = z @ Wg_z^T + b_gate
  gemm_bt<<<dim3(H_ / 64, (B_ * T_) / 64), dim3(256), 0, stream>>>(
      (const void*)z_bf, Wgzbf, b_gate, (void*)a_bf, B_ * T_, H_, H_, 0, 0);

  // scan (cooperative: 128 co-resident WGs required)
  {
    float* hfinal = (float*)d_out + (size_t)B_ * T_ * O_;
    const ushort* zc = z_bf; const ushort* ac = a_bf;
    ushort* hb = hbuf; const float* wg = W_gate; const float* h0c = h0;
    int* flg = flags;
    void* sargs[7] = { (void*)&zc, (void*)&ac, (void*)&hb, (void*)&wg,
                       (void*)&h0c, (void*)&hfinal, (void*)&flg };
    hipLaunchCooperativeKernel((const void*)scan_kernel, dim3(128), dim3(64), sargs, 0, stream);
  }

  // G3: outs[b,t,o] = hs[(t,b),:] @ W_out^T + b_out  (A = hbuf[1..T])
  gemm_bt<<<dim3(O_ / 64, (B_ * T_) / 64), dim3(256), 0, stream>>>(
      (const void*)(hbuf + BH), Woutbf, b_out, d_out, B_ * T_, O_, H_, 0, 1);
}